// Round 3
// baseline (285.273 us; speedup 1.0000x reference)
//
#include <hip/hip_runtime.h>

#define AS1 __attribute__((address_space(1)))
#define AS3 __attribute__((address_space(3)))

typedef short short8 __attribute__((ext_vector_type(8)));
typedef float f32x16 __attribute__((ext_vector_type(16)));

// Problem constants
#define BATCH 4096
#define IN_F 256
#define OUT_F 256
#define HYP 128
#define HX 129            // HYP + 1 (b2g folded in as extra channel, gain 1.0)
#define KP (HX * IN_F)    // 33024 shorts per V row

__device__ __forceinline__ float bf2f(unsigned short u) {
  unsigned v = ((unsigned)u) << 16;
  float f;
  __builtin_memcpy(&f, &v, 4);
  return f;
}
__device__ __forceinline__ unsigned short f2bf(float f) {
  unsigned u;
  __builtin_memcpy(&u, &f, 4);
  unsigned r = u + 0x7fffu + ((u >> 16) & 1u);  // RTNE
  return (unsigned short)(r >> 16);
}

__device__ __forceinline__ void gld_lds16(const unsigned short* g, unsigned short* s) {
  __builtin_amdgcn_global_load_lds((const AS1 unsigned int*)g, (AS3 unsigned int*)s, 16, 0, 0);
}

// ---------------------------------------------------------------------------
// k_buildV: V[o][h*256+i] = bf16( h<128 ? W2g[h][o*256+i] : b2g[o*256+i] )
// ---------------------------------------------------------------------------
__global__ void k_buildV(const float* __restrict__ W2g, const float* __restrict__ b2g,
                         unsigned short* __restrict__ Vb) {
  const int cid = blockIdx.x * 256 + threadIdx.x;  // < 256*129*32
  const int ic = cid & 31;
  const int pair = cid >> 5;        // o*129 + h
  const int h = pair % HX;
  const int o = pair / HX;
  const float* src = (h < HYP) ? (W2g + (size_t)h * (OUT_F * IN_F) + o * IN_F + ic * 8)
                               : (b2g + o * IN_F + ic * 8);
  const float4 v0 = ((const float4*)src)[0];
  const float4 v1 = ((const float4*)src)[1];
  uint4 pk;
  pk.x = (unsigned)f2bf(v0.x) | ((unsigned)f2bf(v0.y) << 16);
  pk.y = (unsigned)f2bf(v0.z) | ((unsigned)f2bf(v0.w) << 16);
  pk.z = (unsigned)f2bf(v1.x) | ((unsigned)f2bf(v1.y) << 16);
  pk.w = (unsigned)f2bf(v1.z) | ((unsigned)f2bf(v1.w) << 16);
  *(uint4*)(Vb + (size_t)o * KP + h * IN_F + ic * 8) = pk;
}

// ---------------------------------------------------------------------------
// k_pre: fused hidden (hg -> eps-clamped bf16, transposed [h][b]; hb) +
//        bias GEMM (initializes d_out) + x -> bf16.
//        Also fills hgsT row 128 with 1.0 (b2g channel gain).
// ---------------------------------------------------------------------------
__global__ __launch_bounds__(256) void k_pre(const float* __restrict__ x,
                                             const float* __restrict__ W1g, const float* __restrict__ b1g,
                                             const float* __restrict__ W1b, const float* __restrict__ b1b,
                                             const float* __restrict__ W2b, const float* __restrict__ b2b,
                                             unsigned short* __restrict__ hgsT,
                                             unsigned short* __restrict__ xb,
                                             float* __restrict__ out) {
  __shared__ float xl[16 * IN_F];                 // 16 KB
  __shared__ float hbl[16 * HYP];                 // 8 KB  [row][h]
  __shared__ unsigned short hgt[HYP * 16];        // 4 KB  [h][row]
  const int t = threadIdx.x;
  const int r0 = blockIdx.x * 16;
  for (int j0 = 0; j0 < 16 * IN_F; j0 += 256) {
    const float v = x[(size_t)r0 * IN_F + j0 + t];
    xl[j0 + t] = v;
    xb[(size_t)r0 * IN_F + j0 + t] = f2bf(v);
  }
  __syncthreads();
  const int h = t & 127;
  const int rb = (t >> 7) * 8;
  float ag[8] = {0.f, 0.f, 0.f, 0.f, 0.f, 0.f, 0.f, 0.f};
  float av[8] = {0.f, 0.f, 0.f, 0.f, 0.f, 0.f, 0.f, 0.f};
  for (int i = 0; i < IN_F; ++i) {
    const float wg = W1g[i * HYP + h];
    const float wb = W1b[i * HYP + h];
#pragma unroll
    for (int r = 0; r < 8; ++r) {
      const float xv = xl[(rb + r) * IN_F + i];
      ag[r] += xv * wg;
      av[r] += xv * wb;
    }
  }
  const float bg = b1g[h], bb = b1b[h];
#pragma unroll
  for (int r = 0; r < 8; ++r) {
    float g = ag[r] + bg; g = g > 0.f ? g : 0.f;
    float v = av[r] + bb; v = v > 0.f ? v : 0.f;
    g = g > 1e-20f ? g : 1e-20f;  // eps-clamp: running-rescale divides by hg
    hgt[h * 16 + rb + r] = f2bf(g);
    hbl[(rb + r) * HYP + h] = v;
  }
  __syncthreads();
  // transposed store: hgsT[h][r0..r0+16)
  {
    const int h2 = t >> 1, part = t & 1;
    const uint4 pk = *(const uint4*)&hgt[h2 * 16 + part * 8];
    *(uint4*)&hgsT[(size_t)h2 * BATCH + r0 + part * 8] = pk;
  }
  if (t < 16) hgsT[(size_t)HYP * BATCH + r0 + t] = 0x3F80;  // row 128 = 1.0
  // out init: out[r0+r][o=t] = b2b + sum_h hb*W2b
  float acc[16];
#pragma unroll
  for (int r = 0; r < 16; ++r) acc[r] = 0.f;
  for (int hh = 0; hh < HYP; ++hh) {
    const float w = W2b[hh * OUT_F + t];
#pragma unroll
    for (int r = 0; r < 16; ++r) acc[r] += hbl[r * HYP + hh] * w;
  }
  const float bo = b2b[t];
#pragma unroll
  for (int r = 0; r < 16; ++r) out[(size_t)(r0 + r) * OUT_F + t] = acc[r] + bo;
}

// ---------------------------------------------------------------------------
// k_gemm (C^T orientation): C[m=o, n=b] = sum_h hg[b,h] * (V[o,h,:] . x[b,:])
// Per-wave: Mo=32 x Nb=128 (4 n-subtiles) -> each LDS V-frag feeds 4 MFMAs.
// x fragments register-resident (i-half split in grid: 64 uint4 -> 128 VGPR).
// hg handled by per-lane running rescale: u *= hg[h-1]/hg[h] before each
// round; final u *= hg[hEnd-1]. hg eps-clamped in k_pre so rcp is safe.
// V staged per-round (8 KB: 32 o-rows x 128 i) via global_load_lds width=16,
// double-buffered; 16-slot XOR swizzle applied on the GLOBAL source side
// (global_load_lds LDS dest must stay lane-contiguous).
// Grid (8 o, 8 b, 8 z=(h-quarter, i-half)) = 512 blocks = 2/CU.
// Epilogue: LDS transpose (pad 34) then coalesced atomicAdd into out.
// ---------------------------------------------------------------------------
__global__ __launch_bounds__(256, 2) void k_gemm(const unsigned short* __restrict__ Vb,
                                                 const unsigned short* __restrict__ hgsT,
                                                 const unsigned short* __restrict__ xb,
                                                 float* __restrict__ out) {
  __shared__ __align__(16) float smem[512 * 34 + 16];  // 69.8 KB; aliased
  unsigned short* Bl = (unsigned short*)smem;          // first 16 KB: 2 x 8 KB bufs
  const int tid = threadIdx.x;
  const int lane = tid & 63;
  const int wave = tid >> 6;
  const int l31 = lane & 31;
  const int hi = lane >> 5;
  const int o0 = blockIdx.x * 32;
  const int b0 = blockIdx.y * 512;
  const int z = blockIdx.z;
  const int zq = z & 3;
  const int hBeg = (HX * zq) >> 2;          // 0,32,64,96
  const int hEnd = (HX * (zq + 1)) >> 2;    // 32,64,96,129
  const int nh = hEnd - hBeg;               // 32,32,32,33
  const int ih = (z >> 2) * 128;            // i-half offset (shorts)

  // ---- preload x fragments: 4 n-subtiles x 8 k16-tiles (128 VGPR) ----
  const int bw = b0 + wave * 128;
  uint4 xf[4][8];
#pragma unroll
  for (int n = 0; n < 4; ++n) {
    const int brow = bw + n * 32 + l31;
#pragma unroll
    for (int t = 0; t < 8; ++t)
      xf[n][t] = *(const uint4*)(xb + (size_t)brow * IN_F + ih + t * 16 + hi * 8);
  }

  // ---- staging geometry: 512 chunks of 16B per round, 2 per thread ----
  // chunk c -> row o = c>>4, slot pos = c&15; source chunk = pos ^ (o&15)
  const int c0 = tid, c1 = tid + 256;
  const int so0 = c0 >> 4, sp0 = (c0 & 15) ^ (so0 & 15);
  const int so1 = c1 >> 4, sp1 = (c1 & 15) ^ (so1 & 15);
  const unsigned short* g0 = Vb + (size_t)(o0 + so0) * KP + ih + sp0 * 8;
  const unsigned short* g1 = Vb + (size_t)(o0 + so1) * KP + ih + sp1 * 8;

  f32x16 zv;
#pragma unroll
  for (int i = 0; i < 16; ++i) zv[i] = 0.0f;
  f32x16 acc0 = zv, acc1 = zv, acc2 = zv, acc3 = zv;

  // running-rescale state (per-lane scalars, one per n-subtile)
  float hgc0 = bf2f(hgsT[(size_t)hBeg * BATCH + bw + 0 * 32 + l31]);
  float hgc1 = bf2f(hgsT[(size_t)hBeg * BATCH + bw + 1 * 32 + l31]);
  float hgc2 = bf2f(hgsT[(size_t)hBeg * BATCH + bw + 2 * 32 + l31]);
  float hgc3 = bf2f(hgsT[(size_t)hBeg * BATCH + bw + 3 * 32 + l31]);

  // prologue: stage round 0 into buf 0
  gld_lds16(g0 + (size_t)hBeg * IN_F, Bl + c0 * 8);
  gld_lds16(g1 + (size_t)hBeg * IN_F, Bl + c1 * 8);
  __syncthreads();

  for (int r = 0; r < nh; ++r) {
    const int h = hBeg + r;
    const int buf = r & 1;
    if (r + 1 < nh) {  // stage next round into other buffer
      const size_t ko = (size_t)(h + 1) * IN_F;
      gld_lds16(g0 + ko, Bl + (buf ^ 1) * 4096 + c0 * 8);
      gld_lds16(g1 + ko, Bl + (buf ^ 1) * 4096 + c1 * 8);
    }
    if (r) {  // rescale: u *= hg[h-1]/hg[h]  (per-lane scalar per n-subtile)
      const float hn0 = bf2f(hgsT[(size_t)h * BATCH + bw + 0 * 32 + l31]);
      const float hn1 = bf2f(hgsT[(size_t)h * BATCH + bw + 1 * 32 + l31]);
      const float hn2 = bf2f(hgsT[(size_t)h * BATCH + bw + 2 * 32 + l31]);
      const float hn3 = bf2f(hgsT[(size_t)h * BATCH + bw + 3 * 32 + l31]);
      const float rt0 = hgc0 * __builtin_amdgcn_rcpf(hn0);
      const float rt1 = hgc1 * __builtin_amdgcn_rcpf(hn1);
      const float rt2 = hgc2 * __builtin_amdgcn_rcpf(hn2);
      const float rt3 = hgc3 * __builtin_amdgcn_rcpf(hn3);
      hgc0 = hn0; hgc1 = hn1; hgc2 = hn2; hgc3 = hn3;
#pragma unroll
      for (int g = 0; g < 16; ++g) {
        acc0[g] *= rt0; acc1[g] *= rt1; acc2[g] *= rt2; acc3[g] *= rt3;
      }
    }
    // V fragments for this round (XOR-swizzled slots; 2-way conflicts only)
    const unsigned short* bp = Bl + buf * 4096;
    short8 va[8];
#pragma unroll
    for (int t = 0; t < 8; ++t) {
      const int slot = (t * 2 + hi) ^ (l31 & 15);
      va[t] = *(const short8*)(bp + l31 * 128 + slot * 8);
    }
#pragma unroll
    for (int t = 0; t < 8; ++t) {
      acc0 = __builtin_amdgcn_mfma_f32_32x32x16_bf16(va[t], __builtin_bit_cast(short8, xf[0][t]), acc0, 0, 0, 0);
      acc1 = __builtin_amdgcn_mfma_f32_32x32x16_bf16(va[t], __builtin_bit_cast(short8, xf[1][t]), acc1, 0, 0, 0);
      acc2 = __builtin_amdgcn_mfma_f32_32x32x16_bf16(va[t], __builtin_bit_cast(short8, xf[2][t]), acc2, 0, 0, 0);
      acc3 = __builtin_amdgcn_mfma_f32_32x32x16_bf16(va[t], __builtin_bit_cast(short8, xf[3][t]), acc3, 0, 0, 0);
    }
    __syncthreads();  // buf reuse guard; drains next-round staging loads
  }

  // final scale: u *= hg[hEnd-1]
#pragma unroll
  for (int g = 0; g < 16; ++g) {
    acc0[g] *= hgc0; acc1[g] *= hgc1; acc2[g] *= hgc2; acc3[g] *= hgc3;
  }

  // ---- epilogue: transpose via LDS (pad 34 -> 2-way-only conflicts) ----
  float* tep = smem;
#pragma unroll
  for (int g = 0; g < 16; ++g) {
    const int orow = (g & 3) + 8 * (g >> 2) + 4 * hi;
    const int bb = wave * 128;
    tep[(bb + 0 * 32 + l31) * 34 + orow] = acc0[g];
    tep[(bb + 1 * 32 + l31) * 34 + orow] = acc1[g];
    tep[(bb + 2 * 32 + l31) * 34 + orow] = acc2[g];
    tep[(bb + 3 * 32 + l31) * 34 + orow] = acc3[g];
  }
  __syncthreads();
  // coalesced atomic accumulate: thread t -> o-quad (t&7)*4, b-rows (t>>3)+32*it
  const int oq = (tid & 7) * 4;
  const int br = tid >> 3;
  for (int it = 0; it < 16; ++it) {
    const int bl = br + 32 * it;
    float* op = &out[(size_t)(b0 + bl) * OUT_F + o0 + oq];
    const float* tp = &tep[bl * 34 + oq];
    atomicAdd(op + 0, tp[0]);
    atomicAdd(op + 1, tp[1]);
    atomicAdd(op + 2, tp[2]);
    atomicAdd(op + 3, tp[3]);
  }
}

// ---------------------------------------------------------------------------
extern "C" void kernel_launch(void* const* d_in, const int* in_sizes, int n_in,
                              void* d_out, int out_size, void* d_ws, size_t ws_size,
                              hipStream_t stream) {
  const float* x = (const float*)d_in[0];
  const float* W1g = (const float*)d_in[1];
  const float* b1g = (const float*)d_in[2];
  const float* W2g = (const float*)d_in[3];
  const float* b2g = (const float*)d_in[4];
  const float* W1b = (const float*)d_in[5];
  const float* b1b = (const float*)d_in[6];
  const float* W2b = (const float*)d_in[7];
  const float* b2b = (const float*)d_in[8];
  float* out = (float*)d_out;

  char* ws = (char*)d_ws;
  const size_t szV = (size_t)OUT_F * KP * 2;        // 16,908,288
  const size_t szHg = (size_t)HX * BATCH * 2;       //  1,056,768 (129 rows)
  unsigned short* Vb = (unsigned short*)ws;
  unsigned short* hgsT = (unsigned short*)(ws + szV);
  unsigned short* xb = (unsigned short*)(ws + szV + szHg);

  hipLaunchKernelGGL(k_buildV, dim3(OUT_F * HX / 8), dim3(256), 0, stream, W2g, b2g, Vb);
  hipLaunchKernelGGL(k_pre, dim3(BATCH / 16), dim3(256), 0, stream,
                     x, W1g, b1g, W1b, b1b, W2b, b2b, hgsT, xb, out);
  hipLaunchKernelGGL(k_gemm, dim3(OUT_F / 32, BATCH / 512, 8), dim3(256), 0, stream,
                     Vb, hgsT, xb, out);
}

// Round 4
// 249.610 us; speedup vs baseline: 1.1429x; 1.1429x over previous
//
#include <hip/hip_runtime.h>

#define AS1 __attribute__((address_space(1)))
#define AS3 __attribute__((address_space(3)))

typedef short short8 __attribute__((ext_vector_type(8)));
typedef float f32x16 __attribute__((ext_vector_type(16)));

// Problem constants
#define BATCH 4096
#define IN_F 256
#define OUT_F 256
#define HYP 128
#define HX 129            // HYP + 1 (b2g folded in as extra channel, gain 1.0)
#define KP (HX * IN_F)    // 33024 shorts per V row
#define NBV (OUT_F * HX / 8)  // 4128 buildV blocks in k_prep

__device__ __forceinline__ float bf2f(unsigned short u) {
  unsigned v = ((unsigned)u) << 16;
  float f;
  __builtin_memcpy(&f, &v, 4);
  return f;
}
__device__ __forceinline__ unsigned short f2bf(float f) {
  unsigned u;
  __builtin_memcpy(&u, &f, 4);
  unsigned r = u + 0x7fffu + ((u >> 16) & 1u);  // RTNE
  return (unsigned short)(r >> 16);
}

__device__ __forceinline__ void gld_lds16(const unsigned short* g, unsigned short* s) {
  __builtin_amdgcn_global_load_lds((const AS1 unsigned int*)g, (AS3 unsigned int*)s, 16, 0, 0);
}

// ---------------------------------------------------------------------------
// k_prep: merged buildV (blocks 0..NBV-1) + pre (blocks NBV..NBV+255).
// buildV: V[o][h*256+i] = bf16( h<128 ? W2g[h][o*256+i] : b2g[o*256+i] )
// pre: hg -> eps-clamped bf16 transposed [h][b] (+row 128 = 1.0); hb;
//      bias GEMM initializes d_out; x -> bf16.
// ---------------------------------------------------------------------------
__global__ __launch_bounds__(256) void k_prep(const float* __restrict__ x,
                                              const float* __restrict__ W1g, const float* __restrict__ b1g,
                                              const float* __restrict__ W2g, const float* __restrict__ b2g,
                                              const float* __restrict__ W1b, const float* __restrict__ b1b,
                                              const float* __restrict__ W2b, const float* __restrict__ b2b,
                                              unsigned short* __restrict__ Vb,
                                              unsigned short* __restrict__ hgsT,
                                              unsigned short* __restrict__ xb,
                                              float* __restrict__ out) {
  __shared__ float xl[16 * IN_F];                 // 16 KB
  __shared__ float hbl[16 * HYP];                 // 8 KB  [row][h]
  __shared__ unsigned short hgt[HYP * 16];        // 4 KB  [h][row]
  const int t = threadIdx.x;

  if (blockIdx.x < NBV) {
    // ---------------- buildV ----------------
    const int cid = blockIdx.x * 256 + t;  // < 256*129*32
    const int ic = cid & 31;
    const int pair = cid >> 5;      // o*129 + h
    const int h = pair % HX;
    const int o = pair / HX;
    const float* src = (h < HYP) ? (W2g + (size_t)h * (OUT_F * IN_F) + o * IN_F + ic * 8)
                                 : (b2g + o * IN_F + ic * 8);
    const float4 v0 = ((const float4*)src)[0];
    const float4 v1 = ((const float4*)src)[1];
    uint4 pk;
    pk.x = (unsigned)f2bf(v0.x) | ((unsigned)f2bf(v0.y) << 16);
    pk.y = (unsigned)f2bf(v0.z) | ((unsigned)f2bf(v0.w) << 16);
    pk.z = (unsigned)f2bf(v1.x) | ((unsigned)f2bf(v1.y) << 16);
    pk.w = (unsigned)f2bf(v1.z) | ((unsigned)f2bf(v1.w) << 16);
    *(uint4*)(Vb + (size_t)o * KP + h * IN_F + ic * 8) = pk;
    return;
  }

  // ---------------- pre ----------------
  const int r0 = (blockIdx.x - NBV) * 16;
  for (int j0 = 0; j0 < 16 * IN_F; j0 += 256) {
    const float v = x[(size_t)r0 * IN_F + j0 + t];
    xl[j0 + t] = v;
    xb[(size_t)r0 * IN_F + j0 + t] = f2bf(v);
  }
  __syncthreads();
  const int h = t & 127;
  const int rb = (t >> 7) * 8;
  float ag[8] = {0.f, 0.f, 0.f, 0.f, 0.f, 0.f, 0.f, 0.f};
  float av[8] = {0.f, 0.f, 0.f, 0.f, 0.f, 0.f, 0.f, 0.f};
  for (int i = 0; i < IN_F; ++i) {
    const float wg = W1g[i * HYP + h];
    const float wb = W1b[i * HYP + h];
#pragma unroll
    for (int r = 0; r < 8; ++r) {
      const float xv = xl[(rb + r) * IN_F + i];
      ag[r] += xv * wg;
      av[r] += xv * wb;
    }
  }
  const float bg = b1g[h], bb = b1b[h];
#pragma unroll
  for (int r = 0; r < 8; ++r) {
    float g = ag[r] + bg; g = g > 0.f ? g : 0.f;
    float v = av[r] + bb; v = v > 0.f ? v : 0.f;
    g = g > 1e-20f ? g : 1e-20f;  // eps-clamp: running-rescale divides by hg
    hgt[h * 16 + rb + r] = f2bf(g);
    hbl[(rb + r) * HYP + h] = v;
  }
  __syncthreads();
  {  // transposed store: hgsT[h][r0..r0+16)
    const int h2 = t >> 1, part = t & 1;
    const uint4 pk = *(const uint4*)&hgt[h2 * 16 + part * 8];
    *(uint4*)&hgsT[(size_t)h2 * BATCH + r0 + part * 8] = pk;
  }
  if (t < 16) hgsT[(size_t)HYP * BATCH + r0 + t] = 0x3F80;  // row 128 = 1.0
  // out init: out[r0+r][o=t] = b2b + sum_h hb*W2b
  float acc[16];
#pragma unroll
  for (int r = 0; r < 16; ++r) acc[r] = 0.f;
  for (int hh = 0; hh < HYP; ++hh) {
    const float w = W2b[hh * OUT_F + t];
#pragma unroll
    for (int r = 0; r < 16; ++r) acc[r] += hbl[r * HYP + hh] * w;
  }
  const float bo = b2b[t];
#pragma unroll
  for (int r = 0; r < 16; ++r) out[(size_t)(r0 + r) * OUT_F + t] = acc[r] + bo;
}

// ---------------------------------------------------------------------------
// k_gemm (C^T): C[m=o, n=b] = sum_h hg[b,h] * (V[o,h,:] . x[b,:])
// Sized to FIT REGISTERS (r3 spilled its 128-VGPR xf array):
//   per wave Mo=32 x Nb=64 -> xf[2][8]=64 VGPR, acc 2x16=32. ~160 total.
// Block: 32 o x 256 b (4 waves), round = 1 h x 128 i (8 k16, 16 MFMA/wave).
// Per-CU per round (2 blocks/CU): MFMA 128x8=1024 cyc > LDS 8x8x12=768 cyc
//   -> compute-bound (CU-level MFMA throughput = 1 per 8 cyc, m119).
// hg pre-staged in LDS (no per-round global latency); per-lane running
// rescale u *= hg[h-1]/hg[h] (hg eps-clamped; scheme validated r3).
// V staged 8 KB/round via global_load_lds w=16, double-buffered, XOR-16
// source-side swizzle. Grid (8 o, 16 b, 4 z=(h-half,i-half)) = 512 blocks;
// grid.x=o => same-o blocks share an XCD (V slice L2-resident).
// Epilogue: LDS transpose (pad 34) + coalesced float-quad atomicAdd.
// ---------------------------------------------------------------------------
__global__ __launch_bounds__(256, 2) void k_gemm(const unsigned short* __restrict__ Vb,
                                                 const unsigned short* __restrict__ hgsT,
                                                 const unsigned short* __restrict__ xb,
                                                 float* __restrict__ out) {
  // compute phase: Bl = smem[0..8192), hgs = smem[8192..8192+65*256)
  // epilogue alias: tep (256*34 floats = 34816 B <= 49664 B)
  __shared__ __align__(16) unsigned short smem[2 * 4096 + 65 * 256];
  unsigned short* Bl = smem;
  unsigned short* hgs = smem + 8192;
  float* tep = (float*)smem;

  const int tid = threadIdx.x;
  const int lane = tid & 63;
  const int wave = tid >> 6;
  const int l31 = lane & 31;
  const int hi = lane >> 5;
  const int o0 = blockIdx.x * 32;
  const int b0 = blockIdx.y * 256;
  const int zh = blockIdx.z & 1;
  const int zi = blockIdx.z >> 1;
  const int hBeg = zh ? 64 : 0;
  const int hEnd = zh ? HX : 64;
  const int nh = hEnd - hBeg;     // 64 or 65
  const int ih = zi * 128;        // i-half offset (shorts)

  // ---- staging geometry: 512 chunks of 16B per round, 2 per thread ----
  // chunk c -> row o = c>>4 (32 rows), slot = c&15; src chunk = slot ^ (row&15)
  const int c0 = tid, c1 = tid + 256;
  const int so0 = c0 >> 4, sp0 = (c0 & 15) ^ (so0 & 15);
  const int so1 = c1 >> 4, sp1 = (c1 & 15) ^ (so1 & 15);
  const unsigned short* g0 = Vb + (size_t)(o0 + so0) * KP + ih + sp0 * 8;
  const unsigned short* g1 = Vb + (size_t)(o0 + so1) * KP + ih + sp1 * 8;

  // prologue: stage round 0 into buf 0 (issue first: longest latency)
  gld_lds16(g0 + (size_t)hBeg * IN_F, Bl + c0 * 8);
  gld_lds16(g1 + (size_t)hBeg * IN_F, Bl + c1 * 8);

  // ---- stage hg tile [h_local][b] -> LDS (uint4 = 8 shorts per store) ----
  for (int idx = tid; idx < nh * 32; idx += 256) {
    const int hl = idx >> 5, c8 = (idx & 31) * 8;
    *(uint4*)&hgs[hl * 256 + c8] =
        *(const uint4*)&hgsT[(size_t)(hBeg + hl) * BATCH + b0 + c8];
  }

  // ---- preload x fragments: 2 n-subtiles x 8 k16 (64 VGPR) ----
  const int bw = b0 + wave * 64;
  uint4 xf0[8], xf1[8];
#pragma unroll
  for (int t = 0; t < 8; ++t) {
    xf0[t] = *(const uint4*)(xb + (size_t)(bw + l31) * IN_F + ih + t * 16 + hi * 8);
    xf1[t] = *(const uint4*)(xb + (size_t)(bw + 32 + l31) * IN_F + ih + t * 16 + hi * 8);
  }

  __syncthreads();  // hgs + round-0 B-tile ready

  f32x16 zv;
#pragma unroll
  for (int i = 0; i < 16; ++i) zv[i] = 0.0f;
  f32x16 acc0 = zv, acc1 = zv;

  // running-rescale state (per-lane scalars, one per n-subtile)
  float hgc0 = bf2f(hgs[wave * 64 + l31]);
  float hgc1 = bf2f(hgs[wave * 64 + 32 + l31]);

  for (int r = 0; r < nh; ++r) {
    const int buf = r & 1;
    if (r + 1 < nh) {  // stage next round into other buffer
      const size_t ko = (size_t)(hBeg + r + 1) * IN_F;
      gld_lds16(g0 + ko, Bl + (buf ^ 1) * 4096 + c0 * 8);
      gld_lds16(g1 + ko, Bl + (buf ^ 1) * 4096 + c1 * 8);
    }
    if (r) {  // rescale: u *= hg[h-1]/hg[h]
      const float hn0 = bf2f(hgs[r * 256 + wave * 64 + l31]);
      const float hn1 = bf2f(hgs[r * 256 + wave * 64 + 32 + l31]);
      const float rt0 = hgc0 * __builtin_amdgcn_rcpf(hn0);
      const float rt1 = hgc1 * __builtin_amdgcn_rcpf(hn1);
      hgc0 = hn0; hgc1 = hn1;
#pragma unroll
      for (int g = 0; g < 16; ++g) {
        acc0[g] *= rt0;
        acc1[g] *= rt1;
      }
    }
    // V fragments (XOR-swizzled slots)
    const unsigned short* bp = Bl + buf * 4096;
    short8 va[8];
#pragma unroll
    for (int t = 0; t < 8; ++t) {
      const int slot = (t * 2 + hi) ^ (l31 & 15);
      va[t] = *(const short8*)(bp + l31 * 128 + slot * 8);
    }
#pragma unroll
    for (int t = 0; t < 8; ++t) {
      acc0 = __builtin_amdgcn_mfma_f32_32x32x16_bf16(va[t], __builtin_bit_cast(short8, xf0[t]), acc0, 0, 0, 0);
      acc1 = __builtin_amdgcn_mfma_f32_32x32x16_bf16(va[t], __builtin_bit_cast(short8, xf1[t]), acc1, 0, 0, 0);
    }
    __syncthreads();  // buf reuse guard; drains staging loads
  }

  // final scale: u *= hg[hEnd-1]
#pragma unroll
  for (int g = 0; g < 16; ++g) {
    acc0[g] *= hgc0;
    acc1[g] *= hgc1;
  }

  // ---- epilogue: transpose via LDS (pad 34 -> only free 2-way conflicts) ----
  // (safe to alias: all waves are past the loop's final barrier; no more
  //  Bl/hgs reads; tep writes then a barrier before readback)
  const int bb = wave * 64;
#pragma unroll
  for (int g = 0; g < 16; ++g) {
    const int orow = (g & 3) + 8 * (g >> 2) + 4 * hi;
    tep[(bb + l31) * 34 + orow] = acc0[g];
    tep[(bb + 32 + l31) * 34 + orow] = acc1[g];
  }
  __syncthreads();
  // coalesced atomic accumulate: thread t -> o-quad (t&7)*4, b-rows (t>>3)+32*it
  const int oq = (tid & 7) * 4;
  const int br = tid >> 3;
  for (int it = 0; it < 8; ++it) {
    const int bl = br + 32 * it;
    float* op = &out[(size_t)(b0 + bl) * OUT_F + o0 + oq];
    const float* tp = &tep[bl * 34 + oq];
    atomicAdd(op + 0, tp[0]);
    atomicAdd(op + 1, tp[1]);
    atomicAdd(op + 2, tp[2]);
    atomicAdd(op + 3, tp[3]);
  }
}

// ---------------------------------------------------------------------------
extern "C" void kernel_launch(void* const* d_in, const int* in_sizes, int n_in,
                              void* d_out, int out_size, void* d_ws, size_t ws_size,
                              hipStream_t stream) {
  const float* x = (const float*)d_in[0];
  const float* W1g = (const float*)d_in[1];
  const float* b1g = (const float*)d_in[2];
  const float* W2g = (const float*)d_in[3];
  const float* b2g = (const float*)d_in[4];
  const float* W1b = (const float*)d_in[5];
  const float* b1b = (const float*)d_in[6];
  const float* W2b = (const float*)d_in[7];
  const float* b2b = (const float*)d_in[8];
  float* out = (float*)d_out;

  char* ws = (char*)d_ws;
  const size_t szV = (size_t)OUT_F * KP * 2;        // 16,908,288
  const size_t szHg = (size_t)HX * BATCH * 2;       //  1,056,768 (129 rows)
  unsigned short* Vb = (unsigned short*)ws;
  unsigned short* hgsT = (unsigned short*)(ws + szV);
  unsigned short* xb = (unsigned short*)(ws + szV + szHg);

  hipLaunchKernelGGL(k_prep, dim3(NBV + BATCH / 16), dim3(256), 0, stream,
                     x, W1g, b1g, W2g, b2g, W1b, b1b, W2b, b2b, Vb, hgsT, xb, out);
  hipLaunchKernelGGL(k_gemm, dim3(OUT_F / 32, BATCH / 256, 4), dim3(256), 0, stream,
                     Vb, hgsT, xb, out);
}